// Round 2
// 718.844 us; speedup vs baseline: 1.3753x; 1.3753x over previous
//
#include <hip/hip_runtime.h>
#include <hip/hip_bf16.h>

using bf16 = __hip_bfloat16;
typedef __bf16 bf16x8 __attribute__((ext_vector_type(8)));
typedef float  f32x4  __attribute__((ext_vector_type(4)));

#define B_ 8
#define S_ 2048
#define H_ 1024
#define M_ (B_ * S_)   // 16384
#define N_ (2 * H_)    // 2048
#define K_ 1024
#define CHUNKS_ 32
#define CLEN_ 64       // 32*64 = 2048 = S_

__device__ __forceinline__ bf16x8 load8f(const float* p) {
  const float4 a = *(const float4*)p;
  const float4 b = *(const float4*)(p + 4);
  bf16x8 r;
  r[0] = (__bf16)a.x; r[1] = (__bf16)a.y; r[2] = (__bf16)a.z; r[3] = (__bf16)a.w;
  r[4] = (__bf16)b.x; r[5] = (__bf16)b.y; r[6] = (__bf16)b.z; r[7] = (__bf16)b.w;
  return r;
}

// f32 -> bf16 bulk convert, 8 elems/thread. n must be multiple of 8.
__global__ __launch_bounds__(256)
void cvt_f32_bf16(const float* __restrict__ src, bf16* __restrict__ dst, long n) {
  const long i = ((long)blockIdx.x * 256 + threadIdx.x) * 8;
  if (i >= n) return;
  *(bf16x8*)(dst + i) = load8f(src + i);
}

// ---------------------------------------------------------------------------
// Fallback GEMM (narrow-workspace path only): m97-style 128x128 tile.
// ---------------------------------------------------------------------------
template <bool WDMA>
__global__ __launch_bounds__(256)
void gemm_bias(const bf16* __restrict__ A, const bf16* __restrict__ Wb,
               const float* __restrict__ Wf, const float* __restrict__ bias,
               bf16* __restrict__ C) {
  __shared__ __align__(16) char lds[16384];
  const int tid  = threadIdx.x;
  const int lane = tid & 63;
  const int wv   = tid >> 6;
  const int wr   = wv >> 1;
  const int wc   = wv & 1;
  const int r15  = lane & 15;
  const int kq   = lane >> 4;
  const int mBase = blockIdx.y * 128;
  const int nBase = blockIdx.x * 128;

  f32x4 acc[4][4];
#pragma unroll
  for (int i = 0; i < 4; ++i)
#pragma unroll
    for (int j = 0; j < 4; ++j)
#pragma unroll
      for (int r = 0; r < 4; ++r) acc[i][j][r] = 0.0f;

  for (int k0 = 0; k0 < K_; k0 += 32) {
    bf16x8 sw[2];
    if constexpr (!WDMA) {
#pragma unroll
      for (int c = 0; c < 2; ++c) {
        const int seg = wv * 2 + c;
        sw[c] = load8f(Wf + (size_t)(nBase + seg * 16 + r15) * K_ + k0 + kq * 8);
      }
    }
    __syncthreads();
#pragma unroll
    for (int c = 0; c < 2; ++c) {
      const int seg = wv * 2 + c;
      const bf16* ga = A + (size_t)(mBase + seg * 16 + r15) * K_ + k0 + kq * 8;
      __builtin_amdgcn_global_load_lds(
          (const __attribute__((address_space(1))) void*)ga,
          (__attribute__((address_space(3))) void*)(lds + seg * 1024), 16, 0, 0);
      if constexpr (WDMA) {
        const bf16* gw = Wb + (size_t)(nBase + seg * 16 + r15) * K_ + k0 + kq * 8;
        __builtin_amdgcn_global_load_lds(
            (const __attribute__((address_space(1))) void*)gw,
            (__attribute__((address_space(3))) void*)(lds + 8192 + seg * 1024), 16, 0, 0);
      } else {
        *(bf16x8*)(lds + 8192 + seg * 1024 + lane * 16) = sw[c];
      }
    }
    __syncthreads();

    bf16x8 af[4], bfr[4];
#pragma unroll
    for (int i = 0; i < 4; ++i)
      af[i] = *(const bf16x8*)(lds + (wr * 4 + i) * 1024 + lane * 16);
#pragma unroll
    for (int j = 0; j < 4; ++j)
      bfr[j] = *(const bf16x8*)(lds + 8192 + (wc * 4 + j) * 1024 + lane * 16);
#pragma unroll
    for (int i = 0; i < 4; ++i)
#pragma unroll
      for (int j = 0; j < 4; ++j)
        acc[i][j] = __builtin_amdgcn_mfma_f32_16x16x32_bf16(af[i], bfr[j],
                                                            acc[i][j], 0, 0, 0);
  }

#pragma unroll
  for (int j = 0; j < 4; ++j) {
    const int col = nBase + wc * 64 + j * 16 + r15;
    const float bv = bias[col];
#pragma unroll
    for (int i = 0; i < 4; ++i) {
      const int row = mBase + wr * 64 + i * 16 + kq * 4;
#pragma unroll
      for (int r = 0; r < 4; ++r)
        C[(size_t)(row + r) * N_ + col] = __float2bfloat16(acc[i][j][r] + bv);
    }
  }
}

// ---------------------------------------------------------------------------
// 256x256 8-phase GEMM (wide path): C[m][n] = sum_k A[m][k]*W[n][k] + bias[n]
// T1 XCD swizzle + T2 XOR-swizzled LDS + T3/T4 8-phase counted-vmcnt + T5.
//
// Geometry: BM=BN=256, BK=64, 8 waves (2M x 4N), per-wave output 128x64,
// acc = f32x4[8][4]. LDS 128 KiB = 2 buffers x {A[2 halves][128x64 bf16],
// B[2 halves][128x64 bf16]}; half-tile = 16 KiB staged by 2 global_load_lds
// per thread (512 thr x 2 x 16B).
//
// T2 swizzle (involution on 16B chunks within a half-tile, row stride 128B):
//   phys_byte = logical_byte ^ ((row & 7) << 4),  row = logical_byte >> 7.
// Staging keeps LDS dest linear (gload_lds HW constraint) and pre-swizzles
// the per-lane GLOBAL source chunk: src_chunk = t ^ ((t>>3)&7).  Fragment
// ds_read_b128 applies the same XOR => lanes 0-15 (rows 0-15, fixed col)
// land on distinct bank-quads, 2-way (free) instead of 16-way.
//
// Phase ledger per iteration (tiles t in buf0 = phases P1-4, t+1 in buf1 =
// P5-8; one half-tile stage per phase; slot is free only after the last
// phase that ds_reads it -- B halves after P2, A halves after P3):
//   P1: ds A0-3,B0-1 (12) stage t+1.A1   P5: ds A0-3,B0-1  stage t+2.A1
//   P2: ds B2-3      (4)  stage t+1.B1   P6: ds B2-3       stage t+2.B1
//   P3: ds A4-7      (8)  stage t+2.B0   P7: ds A4-7       stage t+3.B0
//   P4: --                stage t+2.A0   P8: --            stage t+3.A0
//   vmcnt(4) at end of P4/P8: 6 stages (12 loads) in flight, oldest 4 stages
//   (= next tile complete) must land, newest 2 (4 loads) may remain.
//
// Register hedge: A-fragments are reused (aF dead after P2's MFMA cluster, so
// P3's LD_A overwrites it in program order) -> ~224 VGPR, under the 256 cap
// from __launch_bounds__(512,2); no scratch spills.
// ---------------------------------------------------------------------------
#define BK_    64
#define NT_    (K_ / BK_)   // 16
#define LBUF_  65536
#define LBOFF_ 32768
#define LHALF_ 16384

__global__ __launch_bounds__(512, 2)
void gemm256(const bf16* __restrict__ A, const bf16* __restrict__ W,
             const float* __restrict__ bias, bf16* __restrict__ C) {
  __shared__ __align__(16) char lds[131072];
  const int tid  = threadIdx.x;
  const int lane = tid & 63;
  const int wv   = tid >> 6;   // 0..7
  const int wm   = wv >> 2;    // 0..1  (row half)
  const int wn   = wv & 3;     // 0..3  (64-col strip)
  const int r15  = lane & 15;
  const int kq   = lane >> 4;

  // T1: bijective XCD swizzle. nwg=512, 512%8==0. XCD x = flat%8 gets
  // sw in [x*64, x*64+64) -> row panels [8x,8x+8) x all 8 col tiles:
  // A panels become XCD-local in L2.
  const int flat = blockIdx.x;
  const int sw   = (flat & 7) * 64 + (flat >> 3);
  const int by   = sw >> 3;    // 0..63
  const int bx   = sw & 7;     // 0..7
  const int mBase = by * 256;
  const int nBase = bx * 256;

  // staging: per-thread loop-invariant source/dest offsets
  size_t srcOff[2];
  int dstOff[2];
#pragma unroll
  for (int q = 0; q < 2; ++q) {
    const int t  = q * 512 + tid;                 // 16B chunk id 0..1023
    const int cc = (t & 7) ^ ((t >> 3) & 7);      // pre-swizzled col chunk
    srcOff[q] = (size_t)(t >> 3) * K_ + cc * 8;   // elements
    dstOff[q] = q * 8192 + wv * 1024;             // linear LDS bytes (wave-uniform)
  }
  const bf16* aH[2] = {A + (size_t)mBase * K_, A + (size_t)(mBase + 128) * K_};
  const bf16* wH[2] = {W + (size_t)nBase * K_, W + (size_t)(nBase + 128) * K_};

#define STAGE(GB, LOFF)                                                        \
  { _Pragma("unroll") for (int q_ = 0; q_ < 2; ++q_)                           \
      __builtin_amdgcn_global_load_lds(                                        \
          (const __attribute__((address_space(1))) void*)((GB) + srcOff[q_]),  \
          (__attribute__((address_space(3))) void*)(lds + (LOFF) + dstOff[q_]),\
          16, 0, 0); }

  // fragment read offsets (T2 read-side XOR; row&7 == r15&7)
  const int xsw  = (r15 & 7) << 4;
  const int col0 = (kq * 16) ^ xsw;
  const int col1 = (64 + kq * 16) ^ xsw;
  const int aRow = wm * LHALF_ + r15 * 128;
  const int bRow = LBOFF_ + (wn >> 1) * LHALF_ + ((wn & 1) * 64 + r15) * 128;

  f32x4 acc[8][4];
#pragma unroll
  for (int i = 0; i < 8; ++i)
#pragma unroll
    for (int j = 0; j < 4; ++j)
#pragma unroll
      for (int r = 0; r < 4; ++r) acc[i][j][r] = 0.0f;

  bf16x8 aF[4][2], bF[4][2];

#define LD_A(BO)                                                               \
  { _Pragma("unroll") for (int i_ = 0; i_ < 4; ++i_) {                         \
      aF[i_][0] = *(const bf16x8*)(lds + (BO) + i_ * 2048 + col0);             \
      aF[i_][1] = *(const bf16x8*)(lds + (BO) + i_ * 2048 + col1); } }
  // BO carries aRow (+ 8192 for rows 64..127)

#define LD_B(J0, BO)                                                           \
  { _Pragma("unroll") for (int j_ = 0; j_ < 2; ++j_) {                         \
      bF[(J0) + j_][0] =                                                       \
          *(const bf16x8*)(lds + (BO) + bRow + ((J0) + j_) * 2048 + col0);     \
      bF[(J0) + j_][1] =                                                       \
          *(const bf16x8*)(lds + (BO) + bRow + ((J0) + j_) * 2048 + col1); } }

#define MFMA_Q(I0, J0)                                                         \
  { _Pragma("unroll") for (int i_ = 0; i_ < 4; ++i_)                           \
    _Pragma("unroll") for (int j_ = 0; j_ < 2; ++j_)                           \
    _Pragma("unroll") for (int k_ = 0; k_ < 2; ++k_)                           \
      acc[(I0) + i_][(J0) + j_] = __builtin_amdgcn_mfma_f32_16x16x32_bf16(     \
          aF[i_][k_], bF[(J0) + j_][k_], acc[(I0) + i_][(J0) + j_], 0, 0, 0); }

#define PH_BAR()                                                               \
  __builtin_amdgcn_sched_barrier(0);                                           \
  __builtin_amdgcn_s_barrier();                                                \
  asm volatile("s_waitcnt lgkmcnt(0)" ::: "memory");                           \
  __builtin_amdgcn_sched_barrier(0);                                           \
  __builtin_amdgcn_s_setprio(1);

#define PH_END()                                                               \
  __builtin_amdgcn_s_setprio(0);                                               \
  __builtin_amdgcn_sched_barrier(0);                                           \
  __builtin_amdgcn_s_barrier();

#define PH_END_VM(N)                                                           \
  __builtin_amdgcn_s_setprio(0);                                               \
  __builtin_amdgcn_sched_barrier(0);                                           \
  asm volatile("s_waitcnt vmcnt(" #N ")" ::: "memory");                        \
  __builtin_amdgcn_s_barrier();

  // Prologue: tile0 complete + t1.{B0,A0} in flight (matches steady state).
  STAGE(aH[0], 0);
  STAGE(aH[1], LHALF_);
  STAGE(wH[0], LBOFF_);
  STAGE(wH[1], LBOFF_ + LHALF_);
  STAGE(wH[0] + BK_, LBUF_ + LBOFF_);
  STAGE(aH[0] + BK_, LBUF_);
  asm volatile("s_waitcnt vmcnt(4)" ::: "memory");
  __builtin_amdgcn_s_barrier();

#pragma unroll 1
  for (int t = 0; t < NT_ - 2; t += 2) {
    const int o1 = (t + 1) * BK_, o2 = (t + 2) * BK_, o3 = (t + 3) * BK_;
    // ---- tile t (buf0) ----
    LD_A(aRow); LD_B(0, 0);
    STAGE(aH[1] + o1, LBUF_ + LHALF_);             // t+1.A1
    asm volatile("s_waitcnt lgkmcnt(8)" ::: "memory");
    PH_BAR(); MFMA_Q(0, 0); PH_END();
    LD_B(2, 0);
    STAGE(wH[1] + o1, LBUF_ + LBOFF_ + LHALF_);    // t+1.B1
    PH_BAR(); MFMA_Q(0, 2); PH_END();
    LD_A(aRow + 8192);
    STAGE(wH[0] + o2, LBOFF_);                     // t+2.B0 (buf0.B0 free after P2)
    PH_BAR(); MFMA_Q(4, 0); PH_END();
    STAGE(aH[0] + o2, 0);                          // t+2.A0 (buf0.A0 free after P3)
    PH_BAR(); MFMA_Q(4, 2); PH_END_VM(4);          // t+1 landed, 4 loads in flight
    // ---- tile t+1 (buf1) ----
    LD_A(LBUF_ + aRow); LD_B(0, LBUF_);
    STAGE(aH[1] + o2, LHALF_);                     // t+2.A1
    asm volatile("s_waitcnt lgkmcnt(8)" ::: "memory");
    PH_BAR(); MFMA_Q(0, 0); PH_END();
    LD_B(2, LBUF_);
    STAGE(wH[1] + o2, LBOFF_ + LHALF_);            // t+2.B1
    PH_BAR(); MFMA_Q(0, 2); PH_END();
    LD_A(LBUF_ + aRow + 8192);
    STAGE(wH[0] + o3, LBUF_ + LBOFF_);             // t+3.B0
    PH_BAR(); MFMA_Q(4, 0); PH_END();
    STAGE(aH[0] + o3, LBUF_);                      // t+3.A0
    PH_BAR(); MFMA_Q(4, 2); PH_END_VM(4);          // t+2 landed
  }

  // Tail: tiles 14 (buf0) and 15 (buf1); only t15.{A1,B1} left to stage.
  {
    const int o1 = (NT_ - 1) * BK_;
    LD_A(aRow); LD_B(0, 0);
    STAGE(aH[1] + o1, LBUF_ + LHALF_);             // t15.A1
    asm volatile("s_waitcnt lgkmcnt(8)" ::: "memory");
    PH_BAR(); MFMA_Q(0, 0); PH_END();
    LD_B(2, 0);
    STAGE(wH[1] + o1, LBUF_ + LBOFF_ + LHALF_);    // t15.B1
    PH_BAR(); MFMA_Q(0, 2); PH_END();
    LD_A(aRow + 8192);
    PH_BAR(); MFMA_Q(4, 0); PH_END();
    PH_BAR(); MFMA_Q(4, 2); PH_END_VM(0);          // t15 fully landed
    // tile 15, no stages
    LD_A(LBUF_ + aRow); LD_B(0, LBUF_);
    PH_BAR(); MFMA_Q(0, 0); PH_END();
    LD_B(2, LBUF_);
    PH_BAR(); MFMA_Q(0, 2); PH_END();
    LD_A(LBUF_ + aRow + 8192);
    PH_BAR(); MFMA_Q(4, 0); PH_END();
    PH_BAR(); MFMA_Q(4, 2);
    __builtin_amdgcn_s_setprio(0);
  }

  // Epilogue. C/D layout: col = lane&15, row = (lane>>4)*4 + r (r3-verified).
#pragma unroll
  for (int j = 0; j < 4; ++j) {
    const int col = nBase + wn * 64 + j * 16 + r15;
    const float bv = bias[col];
#pragma unroll
    for (int i = 0; i < 8; ++i) {
      const int row0 = mBase + wm * 128 + i * 16 + kq * 4;
#pragma unroll
      for (int r = 0; r < 4; ++r)
        C[(size_t)(row0 + r) * N_ + col] = __float2bfloat16(acc[i][j][r] + bv);
    }
  }
#undef STAGE
#undef LD_A
#undef LD_B
#undef MFMA_Q
#undef PH_BAR
#undef PH_END
#undef PH_END_VM
}

// ---------------------------------------------------------------------------
// Scan pointwise math:  h_t = ca*h_{t-1} + cb
// ---------------------------------------------------------------------------
__device__ __forceinline__ float rcpf(float x) { return __builtin_amdgcn_rcpf(x); }

__device__ __forceinline__ void step_coeffs(float gate, float hidden,
                                            float& ca, float& cb) {
  const float e1 = __expf(gate);
  ca = rcpf(1.0f + e1);
  const float z = 1.0f - ca;
  float g;
  if (hidden >= 0.0f) {
    g = hidden + 0.5f;
  } else {
    const float e2 = __expf(hidden);
    g = e2 * rcpf(1.0f + e2);
  }
  cb = z * g;
}

__device__ __forceinline__ float g_of(float x) {
  if (x >= 0.0f) return x + 0.5f;
  const float e = __expf(x);
  return e * rcpf(1.0f + e);
}

__global__ __launch_bounds__(256)
void scan_chunk(const bf16* __restrict__ gh, float2* __restrict__ sAB) {
  const int tx = threadIdx.x, bx = blockIdx.x;
  const int hb = bx & 3, b = (bx >> 2) & 7, j = bx >> 5;
  const int hh = hb * 256 + tx;
  const int c = b * 1024 + hh;
  const bf16* gbase = gh + ((size_t)(b * S_ + j * CLEN_)) * N_ + hh;
  float A = 1.0f, Bc = 0.0f;
#pragma unroll 8
  for (int t = 0; t < CLEN_; ++t) {
    const float gate   = __bfloat162float(gbase[(size_t)t * N_]);
    const float hidden = __bfloat162float(gbase[(size_t)t * N_ + H_]);
    float ca, cb;
    step_coeffs(gate, hidden, ca, cb);
    A *= ca;
    Bc = ca * Bc + cb;
  }
  sAB[j * (B_ * H_) + c] = make_float2(A, Bc);
}

__global__ __launch_bounds__(256)
void scan_carry(const float2* __restrict__ sAB, const float* __restrict__ hprev,
                float* __restrict__ carry) {
  const int c = blockIdx.x * 256 + threadIdx.x;
  float Hc = g_of(hprev[c]);
#pragma unroll
  for (int j = 0; j < CHUNKS_; ++j) {
    carry[j * (B_ * H_) + c] = Hc;
    const float2 ab = sAB[j * (B_ * H_) + c];
    Hc = ab.x * Hc + ab.y;
  }
}

__global__ __launch_bounds__(256)
void scan_apply(const bf16* __restrict__ gh, const float* __restrict__ carry,
                const float* rin, float* rout, bf16* gout,
                float* __restrict__ finals) {
  const int tx = threadIdx.x, bx = blockIdx.x;
  const int hb = bx & 3, b = (bx >> 2) & 7, j = bx >> 5;
  const int hh = hb * 256 + tx;
  const int c = b * 1024 + hh;
  const size_t base = ((size_t)(b * S_ + j * CLEN_)) * H_ + hh;
  const bf16* gbase = gh + ((size_t)(b * S_ + j * CLEN_)) * N_ + hh;
  float h = carry[j * (B_ * H_) + c];
#pragma unroll 4
  for (int t = 0; t < CLEN_; ++t) {
    const float gate   = __bfloat162float(gbase[(size_t)t * N_]);
    const float hidden = __bfloat162float(gbase[(size_t)t * N_ + H_]);
    float ca, cb;
    step_coeffs(gate, hidden, ca, cb);
    h = ca * h + cb;
    const float r = h + rin[base + (size_t)t * H_];
    rout[base + (size_t)t * H_] = r;
    if (gout) gout[base + (size_t)t * H_] = __float2bfloat16(r);
  }
  if (j == CHUNKS_ - 1) finals[c] = h;
}

// ---------------------------------------------------------------------------
extern "C" void kernel_launch(void* const* d_in, const int* in_sizes, int n_in,
                              void* d_out, int out_size, void* d_ws,
                              size_t ws_size, hipStream_t stream) {
  const float* x  = (const float*)d_in[0];
  const float* h0 = (const float*)d_in[1];
  const float* W0 = (const float*)d_in[2];
  const float* b0 = (const float*)d_in[3];
  const float* Wl = (const float*)d_in[4];
  const float* bl = (const float*)d_in[5];
  float* out    = (float*)d_out;
  float* finals = out + (size_t)M_ * H_;

  char* ws = (char*)d_ws;
  bf16* gh   = (bf16*)ws;                   // 64 MB: (M_, 2H)
  bf16* bufA = (bf16*)(ws + (64u << 20));   // 32 MB: bf16 A for current layer

  const bool wide = ws_size >= ((size_t)115 << 20);
  bf16*   wb    = wide ? (bf16*)(ws + (96u << 20)) : nullptr;       // 16 MB
  float2* sAB   = (float2*)(ws + ((wide ? 112u : 96u) << 20));      // 2 MB
  float*  carry = (float*)(ws + ((wide ? 114u : 98u) << 20));       // 1 MB

  cvt_f32_bf16<<<dim3(M_ * K_ / 8 / 256), 256, 0, stream>>>(x, bufA, (long)M_ * K_);
  if (wide) {
    cvt_f32_bf16<<<dim3(N_ * K_ / 8 / 256), 256, 0, stream>>>(W0, wb, (long)N_ * K_);
    cvt_f32_bf16<<<dim3(3 * N_ * K_ / 8 / 256), 256, 0, stream>>>(
        Wl, wb + (size_t)N_ * K_, (long)3 * N_ * K_);
  }

  for (int l = 0; l < 4; ++l) {
    const float* Wf = (l == 0) ? W0 : Wl + (size_t)(l - 1) * N_ * K_;
    const float* bi = (l == 0) ? b0 : bl + (size_t)(l - 1) * N_;
    if (wide) {
      gemm256<<<dim3(512), 512, 0, stream>>>(
          bufA, wb + (size_t)l * N_ * K_, bi, gh);
    } else {
      gemm_bias<false><<<dim3(16, 128), 256, 0, stream>>>(
          bufA, nullptr, Wf, bi, gh);
    }
    scan_chunk<<<dim3(4 * 8 * CHUNKS_), 256, 0, stream>>>(gh, sAB);
    scan_carry<<<dim3(32), 256, 0, stream>>>(sAB, h0 + (size_t)l * B_ * H_, carry);
    scan_apply<<<dim3(4 * 8 * CHUNKS_), 256, 0, stream>>>(
        gh, carry, (l == 0) ? x : out, out, (l == 3) ? nullptr : bufA,
        finals + (size_t)l * B_ * H_);
  }
}